// Round 3
// baseline (347.667 us; speedup 1.0000x reference)
//
#include <hip/hip_runtime.h>

static constexpr int   H         = 4096;
static constexpr int   TPB       = 256;        // 4 waves/block, 1 wave per output row
static constexpr int   NB        = H / 4;      // 1024 blocks
static constexpr int   MAX_STEPS = 16;
static constexpr float EPS       = 0.01f;

// ws layout (floats): v0[H] | wih0[H] | halt[32] | h[(MAX_STEPS+1) * H]
static constexpr int WS_V0   = 0;
static constexpr int WS_WIH0 = H;
static constexpr int WS_HALT = 2 * H;
static constexpr int WS_H    = 2 * H + 32;

__device__ __forceinline__ float wave_reduce(float v) {
    #pragma unroll
    for (int off = 32; off > 0; off >>= 1) v += __shfl_down(v, off);
    return v;
}

__device__ __forceinline__ float sigmoidf(float z) {
    return 1.f / (1.f + __expf(-z));
}

// ---------- A: v0 = W_ih[:,1:]@x + b_ih + b_hh ; wih0 ; h0 = s ; halt = 0 ----------
__global__ void __launch_bounds__(TPB)
k_init(const float* __restrict__ x, const float* __restrict__ s,
       const float* __restrict__ Wih, const float* __restrict__ bih,
       const float* __restrict__ bhh, float* __restrict__ ws)
{
    __shared__ float xs[H];
    const int tid = threadIdx.x, lane = tid & 63, wave = tid >> 6;
    const int row = blockIdx.x * 4 + wave;

    for (int i = tid; i < H / 4; i += TPB)
        ((float4*)xs)[i] = ((const float4*)x)[i];
    __syncthreads();

    // W_ih row stride is H+1 = 4097; we need columns 1..4096 of this row.
    const long long off0 = (long long)row * (H + 1) + 1;   // element offset of W_ih[row][1]
    const int a = (int)((4 - (off0 & 3)) & 3);             // scalars until 16B alignment
    float acc = 0.f;
    if (lane < a) acc += Wih[off0 + lane] * xs[lane];
    const int nvec = (H - a) >> 2;                         // remaining float4s
    const float4* wv = (const float4*)(Wih + off0 + a);
    for (int i = lane; i < nvec; i += 64) {
        float4 w  = wv[i];
        const int e = a + i * 4;
        acc = fmaf(w.x, xs[e],     acc);
        acc = fmaf(w.y, xs[e + 1], acc);
        acc = fmaf(w.z, xs[e + 2], acc);
        acc = fmaf(w.w, xs[e + 3], acc);
    }
    const int tail  = (H - a) & 3;
    const int tbase = a + nvec * 4;
    if (lane < tail) acc += Wih[off0 + tbase + lane] * xs[tbase + lane];
    acc = wave_reduce(acc);
    if (lane == 0) {
        ws[WS_V0 + row]   = acc + bih[row] + bhh[row];
        ws[WS_WIH0 + row] = Wih[(long long)row * (H + 1)]; // W_ih[row][0]
    }
    const int g = blockIdx.x * TPB + tid;
    if (g < H) ws[WS_H + g] = s[g];
    if (blockIdx.x == 0 && tid < MAX_STEPS) ws[WS_HALT + tid] = 0.f;
}

// ---------- B_t: skip if halted before t, else h_{t+1} = tanh(v0 + [t==0]wih0 + W_hh@h_t) ----------
__global__ void __launch_bounds__(TPB)
k_step(int t, const float* __restrict__ Whh, const float* __restrict__ whalt,
       const float* __restrict__ bhalt, float* __restrict__ ws)
{
    // Uniform halting check: halt[j] (j<t) were finalized by earlier kernels
    // on the same stream; every thread reads the same values.
    const float bh = bhalt[0];
    float cum = 0.f;
    for (int j = 0; j < t; ++j) {
        cum += sigmoidf(ws[WS_HALT + j] + bh);
        if (cum >= 1.f - EPS) return;          // already halted: nothing to do
    }

    __shared__ float hs[H];
    const float* hin  = ws + WS_H + (long long)t * H;
    float*       hout = ws + WS_H + (long long)(t + 1) * H;
    const int tid = threadIdx.x, lane = tid & 63, wave = tid >> 6;
    for (int i = tid; i < H / 4; i += TPB)
        ((float4*)hs)[i] = ((const float4*)hin)[i];
    __syncthreads();

    const int row = blockIdx.x * 4 + wave;
    const float4* Wr = (const float4*)(Whh + (long long)row * H);
    float acc = 0.f;
    #pragma unroll
    for (int it = 0; it < 16; ++it) {
        const int idx = it * 64 + lane;        // float4 index, coalesced per wave
        float4 w  = Wr[idx];
        float4 hv = ((const float4*)hs)[idx];
        acc = fmaf(w.x, hv.x, acc);
        acc = fmaf(w.y, hv.y, acc);
        acc = fmaf(w.z, hv.z, acc);
        acc = fmaf(w.w, hv.w, acc);
    }
    acc = wave_reduce(acc);
    if (lane == 0) {
        float pre  = acc + ws[WS_V0 + row] + (t == 0 ? ws[WS_WIH0 + row] : 0.f);
        float hval = tanhf(pre);
        hout[row] = hval;
        atomicAdd(&ws[WS_HALT + t], whalt[row] * hval);
    }
}

// ---------- D: pick N, out = W_out@h_{N+1} + b_out ; s_new = h_{N+1} ; ponder = N ----------
__global__ void __launch_bounds__(TPB)
k_final(const float* __restrict__ Wout, const float* __restrict__ bout,
        const float* __restrict__ bhalt, float* __restrict__ ws,
        float* __restrict__ out)
{
    const float bh = bhalt[0];
    float cum = 0.f;
    int N = MAX_STEPS - 1;
    for (int j = 0; j < MAX_STEPS; ++j) {
        cum += sigmoidf(ws[WS_HALT + j] + bh);
        if (cum >= 1.f - EPS) { N = j; break; }
    }

    __shared__ float hs[H];
    const float* hN = ws + WS_H + (long long)(N + 1) * H;
    const int tid = threadIdx.x, lane = tid & 63, wave = tid >> 6;
    for (int i = tid; i < H / 4; i += TPB)
        ((float4*)hs)[i] = ((const float4*)hN)[i];
    __syncthreads();

    const int row = blockIdx.x * 4 + wave;
    const float4* Wr = (const float4*)(Wout + (long long)row * H);
    float acc = 0.f;
    #pragma unroll
    for (int it = 0; it < 16; ++it) {
        const int idx = it * 64 + lane;
        float4 w  = Wr[idx];
        float4 hv = ((const float4*)hs)[idx];
        acc = fmaf(w.x, hv.x, acc);
        acc = fmaf(w.y, hv.y, acc);
        acc = fmaf(w.z, hv.z, acc);
        acc = fmaf(w.w, hv.w, acc);
    }
    acc = wave_reduce(acc);
    if (lane == 0) {
        out[row]     = acc + bout[row];
        out[H + row] = hs[row];
        if (row == 0) out[2 * H] = (float)N;
    }
}

extern "C" void kernel_launch(void* const* d_in, const int* in_sizes, int n_in,
                              void* d_out, int out_size, void* d_ws, size_t ws_size,
                              hipStream_t stream) {
    const float* x     = (const float*)d_in[0];
    const float* s     = (const float*)d_in[1];
    const float* Wih   = (const float*)d_in[2];
    const float* bih   = (const float*)d_in[3];
    const float* Whh   = (const float*)d_in[4];
    const float* bhh   = (const float*)d_in[5];
    const float* whalt = (const float*)d_in[6];
    const float* bhalt = (const float*)d_in[7];
    const float* Wout  = (const float*)d_in[8];
    const float* bout  = (const float*)d_in[9];
    float* out = (float*)d_out;
    float* ws  = (float*)d_ws;

    k_init<<<NB, TPB, 0, stream>>>(x, s, Wih, bih, bhh, ws);
    for (int t = 0; t < MAX_STEPS; ++t)
        k_step<<<NB, TPB, 0, stream>>>(t, Whh, whalt, bhalt, ws);
    k_final<<<NB, TPB, 0, stream>>>(Wout, bout, bhalt, ws, out);
}

// Round 7
// 259.546 us; speedup vs baseline: 1.3395x; 1.3395x over previous
//
#include <hip/hip_runtime.h>

static constexpr int   H           = 4096;
static constexpr int   TPB         = 256;      // 4 waves/block, 1 wave per output row
static constexpr int   NB          = H / 4;    // 1024 blocks
static constexpr int   MAX_STEPS   = 16;
static constexpr float EPS         = 0.01f;
static constexpr int   SLOTS       = 64;       // halt partial slots per step
static constexpr int   SLOT_STRIDE = 32;       // floats (128 B) -> one L2 line per slot

// ws layout (floats):
//   v0[H] | wih0[H] | totals[32] | partials[MAX_STEPS][SLOTS*SLOT_STRIDE] | h[2][H]
static constexpr int WS_V0   = 0;
static constexpr int WS_WIH0 = H;
static constexpr int WS_TOT  = 2 * H;
static constexpr int WS_PART = 2 * H + 32;
static constexpr int WS_H    = WS_PART + MAX_STEPS * SLOTS * SLOT_STRIDE;
// total = 8192 + 32 + 32768 + 8192 = 49184 floats (~197 KB)

__device__ __forceinline__ float wave_reduce(float v) {
    #pragma unroll
    for (int off = 32; off > 0; off >>= 1) v += __shfl_down(v, off);
    return v;
}
__device__ __forceinline__ float sigmoidf(float z) { return 1.f / (1.f + __expf(-z)); }

// ---------- A: v0 = W_ih[:,1:]@x + b_ih + b_hh ; wih0 ; h[0] = s ; zero totals+partials ----------
// Matvec body identical to the R3 version that is proven to run on HW.
__global__ void __launch_bounds__(TPB)
k_init(const float* __restrict__ x, const float* __restrict__ s,
       const float* __restrict__ Wih, const float* __restrict__ bih,
       const float* __restrict__ bhh, float* __restrict__ ws)
{
    __shared__ float xs[H];
    const int tid = threadIdx.x, lane = tid & 63, wave = tid >> 6;
    const int row = blockIdx.x * 4 + wave;

    for (int i = tid; i < H / 4; i += TPB)
        ((float4*)xs)[i] = ((const float4*)x)[i];
    __syncthreads();

    // W_ih row stride is H+1 = 4097; we need columns 1..4096 of this row.
    const long long off0 = (long long)row * (H + 1) + 1;   // element offset of W_ih[row][1]
    const int a = (int)((4 - (off0 & 3)) & 3);             // scalars until 16B alignment
    float acc = 0.f;
    if (lane < a) acc += Wih[off0 + lane] * xs[lane];
    const int nvec = (H - a) >> 2;                         // remaining float4s
    const float4* wv = (const float4*)(Wih + off0 + a);
    for (int i = lane; i < nvec; i += 64) {
        float4 w  = wv[i];
        const int e = a + i * 4;
        acc = fmaf(w.x, xs[e],     acc);
        acc = fmaf(w.y, xs[e + 1], acc);
        acc = fmaf(w.z, xs[e + 2], acc);
        acc = fmaf(w.w, xs[e + 3], acc);
    }
    const int tail  = (H - a) & 3;
    const int tbase = a + nvec * 4;
    if (lane < tail) acc += Wih[off0 + tbase + lane] * xs[tbase + lane];
    acc = wave_reduce(acc);
    if (lane == 0) {
        ws[WS_V0 + row]   = acc + bih[row] + bhh[row];
        ws[WS_WIH0 + row] = Wih[(long long)row * (H + 1)]; // W_ih[row][0]
    }

    const int gid = blockIdx.x * TPB + tid;
    if (gid < H) ws[WS_H + gid] = s[gid];                  // h buffer 0 = s
    if (gid < 32 + MAX_STEPS * SLOTS * SLOT_STRIDE)        // zero totals + partials
        ws[WS_TOT + gid] = 0.f;
}

// ---------- B_t: uniform halting check, else h[(t+1)&1] = tanh(v0 + [t==0]wih0 + W_hh@h[t&1]) ----------
__global__ void __launch_bounds__(TPB, 4)
k_step(int t, const float* __restrict__ Whh, const float* __restrict__ whalt,
       const float* __restrict__ bhalt, float* __restrict__ ws)
{
    const float bh = bhalt[0];

    // Memoized per-step totals from earlier dispatches (serialized on the stream).
    float cum = 0.f;
    for (int j = 0; j < t - 1; ++j) {
        cum += sigmoidf(ws[WS_TOT + j] + bh);
        if (cum >= 1.f - EPS) return;                      // halted earlier: no-op dispatch
    }
    if (t >= 1) {                                          // reduce step t-1's 64 spread partials
        float sj = 0.f;
        const float* p = ws + WS_PART + (size_t)(t - 1) * (SLOTS * SLOT_STRIDE);
        #pragma unroll
        for (int g = 0; g < SLOTS; ++g) sj += p[g * SLOT_STRIDE];
        if (threadIdx.x == 0) ws[WS_TOT + (t - 1)] = sj;   // memoize (same value from every block)
        cum += sigmoidf(sj + bh);
        if (cum >= 1.f - EPS) return;
    }

    // ---- heavy path: one wave per output row ----
    __shared__ float hs[H];
    __shared__ float hred[4];
    const int tid = threadIdx.x, lane = tid & 63, wave = tid >> 6;
    const float* hin  = ws + WS_H + (size_t)(t & 1) * H;
    float*       hout = ws + WS_H + (size_t)((t + 1) & 1) * H;
    for (int i = tid; i < H / 4; i += TPB)
        ((float4*)hs)[i] = ((const float4*)hin)[i];
    __syncthreads();

    const int row = blockIdx.x * 4 + wave;
    const float4* Wr = (const float4*)(Whh + (size_t)row * H);
    float4 w[16];
    #pragma unroll
    for (int it = 0; it < 16; ++it) w[it] = Wr[it * 64 + lane];   // 16 loads in flight
    float acc = 0.f;
    #pragma unroll
    for (int it = 0; it < 16; ++it) {
        float4 hv = ((const float4*)hs)[it * 64 + lane];
        acc = fmaf(w[it].x, hv.x, acc);
        acc = fmaf(w[it].y, hv.y, acc);
        acc = fmaf(w[it].z, hv.z, acc);
        acc = fmaf(w[it].w, hv.w, acc);
    }
    acc = wave_reduce(acc);
    if (lane == 0) {
        float pre  = acc + ws[WS_V0 + row] + (t == 0 ? ws[WS_WIH0 + row] : 0.f);
        float hval = tanhf(pre);
        hout[row]  = hval;
        hred[wave] = whalt[row] * hval;
    }
    __syncthreads();
    if (tid == 0) {                                        // 1 atomic per block, 64-way line spread
        float v = hred[0] + hred[1] + hred[2] + hred[3];
        atomicAdd(&ws[WS_PART + (size_t)t * (SLOTS * SLOT_STRIDE)
                      + (blockIdx.x & (SLOTS - 1)) * SLOT_STRIDE], v);
    }
}

// ---------- D: pick N, out = W_out@h_{N+1} + b_out ; s_new = h_{N+1} ; ponder = N ----------
__global__ void __launch_bounds__(TPB, 4)
k_final(const float* __restrict__ Wout, const float* __restrict__ bout,
        const float* __restrict__ bhalt, float* __restrict__ ws,
        float* __restrict__ out)
{
    const float bh = bhalt[0];
    float cum = 0.f;
    int N = MAX_STEPS - 1;
    for (int j = 0; j < MAX_STEPS; ++j) {
        float sj;
        if (j < MAX_STEPS - 1) sj = ws[WS_TOT + j];
        else {                                             // step 15 total never memoized
            sj = 0.f;
            const float* p = ws + WS_PART + (size_t)(MAX_STEPS - 1) * (SLOTS * SLOT_STRIDE);
            #pragma unroll
            for (int g = 0; g < SLOTS; ++g) sj += p[g * SLOT_STRIDE];
        }
        cum += sigmoidf(sj + bh);
        if (cum >= 1.f - EPS) { N = j; break; }
    }

    __shared__ float hs[H];
    const float* hN = ws + WS_H + (size_t)((N + 1) & 1) * H;   // h_{N+1} (double buffer)
    const int tid = threadIdx.x, lane = tid & 63, wave = tid >> 6;
    for (int i = tid; i < H / 4; i += TPB)
        ((float4*)hs)[i] = ((const float4*)hN)[i];
    __syncthreads();

    const int row = blockIdx.x * 4 + wave;
    const float4* Wr = (const float4*)(Wout + (size_t)row * H);
    float4 w[16];
    #pragma unroll
    for (int it = 0; it < 16; ++it) w[it] = Wr[it * 64 + lane];
    float acc = 0.f;
    #pragma unroll
    for (int it = 0; it < 16; ++it) {
        float4 hv = ((const float4*)hs)[it * 64 + lane];
        acc = fmaf(w[it].x, hv.x, acc);
        acc = fmaf(w[it].y, hv.y, acc);
        acc = fmaf(w[it].z, hv.z, acc);
        acc = fmaf(w[it].w, hv.w, acc);
    }
    acc = wave_reduce(acc);
    if (lane == 0) {
        out[row]     = acc + bout[row];
        out[H + row] = hs[row];
        if (row == 0) out[2 * H] = (float)N;
    }
}

extern "C" void kernel_launch(void* const* d_in, const int* in_sizes, int n_in,
                              void* d_out, int out_size, void* d_ws, size_t ws_size,
                              hipStream_t stream) {
    const float* x     = (const float*)d_in[0];
    const float* s     = (const float*)d_in[1];
    const float* Wih   = (const float*)d_in[2];
    const float* bih   = (const float*)d_in[3];
    const float* Whh   = (const float*)d_in[4];
    const float* bhh   = (const float*)d_in[5];
    const float* whalt = (const float*)d_in[6];
    const float* bhalt = (const float*)d_in[7];
    const float* Wout  = (const float*)d_in[8];
    const float* bout  = (const float*)d_in[9];
    float* out = (float*)d_out;
    float* ws  = (float*)d_ws;

    k_init<<<NB, TPB, 0, stream>>>(x, s, Wih, bih, bhh, ws);
    for (int t = 0; t < MAX_STEPS; ++t)
        k_step<<<NB, TPB, 0, stream>>>(t, Whh, whalt, bhalt, ws);
    k_final<<<NB, TPB, 0, stream>>>(Wout, bout, bhalt, ws, out);
}